// Round 18
// baseline (106.353 us; speedup 1.0000x reference)
//
#include <hip/hip_runtime.h>
#include <stdint.h>

typedef unsigned short u16;
typedef __attribute__((ext_vector_type(8))) short short8;
typedef __attribute__((ext_vector_type(4))) float f32x4;
typedef __attribute__((ext_vector_type(2))) uint32_t u32x2;

#define B_      16
#define L_      1024
#define H_      1024
#define G_      128
#define M_TOT   16368            // B*(L-1)
#define K_TOT   3072
#define OUT_SEG 2095104          // M_TOT*G_
#define KL_IDX  (4*OUT_SEG)
#define KL_BLOCKS 4092           // M_TOT / 4 exactly

// ws layout
#define WS_WTP_OFF   0           // bf16 W' k-interleaved [384][512][8] = 3,145,728 B
#define WS_BIAS_OFF  3145728     // float[512]
#define WS_PART_OFF  3147776     // float[4092] block partials

__device__ inline u16 f2bf(float f) {
    union { float f; uint32_t u; } x; x.f = f;
    uint32_t u = x.u;
    return (u16)((u + 0x7fffu + ((u >> 16) & 1u)) >> 16);
}

// ---------------- prep: wtp[k>>3][n][k&7] bf16 + bias[512] -------------------
__global__ __launch_bounds__(256) void prep_kernel(
    const float* __restrict__ Wzm, const float* __restrict__ bzm,
    const float* __restrict__ Wzv, const float* __restrict__ bzv,
    const float* __restrict__ Wqm, const float* __restrict__ bqm,
    const float* __restrict__ Wqv, const float* __restrict__ bqv,
    u16* __restrict__ wtp, float* __restrict__ bias)
{
    int n = blockIdx.x;                 // 0..511 (output column)
    int tid = threadIdx.x;
    const float* W; const float* bsrc; int g; int kmax;
    if (n < 128)      { W = Wzm; bsrc = bzm; g = n;       kmax = 2048; }
    else if (n < 256) { W = Wzv; bsrc = bzv; g = n - 128; kmax = 2048; }
    else if (n < 384) { W = Wqm; bsrc = bqm; g = n - 256; kmax = 3072; }
    else              { W = Wqv; bsrc = bqv; g = n - 384; kmax = 3072; }
    if (tid == 0) bias[n] = bsrc[g];
    #pragma unroll
    for (int i = 0; i < 12; ++i) {
        int k = i * 256 + tid;
        float v = (k < kmax) ? W[(size_t)k * G_ + g] : 0.0f;
        wtp[(size_t)(k >> 3) * 4096 + n * 8 + (k & 7)] = f2bf(v);
    }
}

// ---------------- GEMM: out[m, 0:512] = ce @ W' + bias ----------------------
// BM=128, BN=128, BK=64, 4 waves (2x2 of 64x64), grid 512 -> 2 blocks/CU.
// A: global f32x4 -> named P/Q reg sets (2-deep) -> cvt_pk bf16 -> swizzled
//    ds_write_b64 (R17 path, LDS 2x16KB = 32KB total).
// B: NO LDS. Direct global->VGPR from k-interleaved wtp (L2-hot, 256B
//    contiguous per 16-lane group), double-buffered BX/BY one phase ahead.
// Counted vmcnt: per phase issue BFRAG(t+1)[8] then LOADA(t+2)[8];
// WAITV(16) drains exactly {B(t), A(t+1)}. No vmcnt(0) in the loop.
__global__ __launch_bounds__(256, 2) void gemm_kernel(
    const float* __restrict__ events, const float* __restrict__ contexts,
    const u16* __restrict__ wtp, const float* __restrict__ bias,
    float* __restrict__ out)
{
    __shared__ u16 Ab[2][128 * 64];   // bf16 A tiles, swizzled (16 KB each)

    const int tid = threadIdx.x;
    const int bid = blockIdx.x;
    // 4 nb-blocks of an A panel share bid&7 -> same XCD.
    const int xx  = bid & 7;
    const int jj  = bid >> 3;            // 0..63
    const int nb  = jj & 3;
    const int mp  = (jj >> 2) * 8 + xx;  // 0..127
    const int m0  = mp * 128;

    const int lane = tid & 63;
    const int w    = tid >> 6;           // 0..3
    const int wm   = (w >> 1) * 64;
    const int wn   = (w & 1) * 64;
    const int lr   = lane & 15;
    const int kg   = lane >> 4;          // 0..3

    // ---- A staging: rows r0=tid>>2 and r0+64; q=tid&3 (R17 layout) ----
    const int r0 = tid >> 2;
    const int q  = tid & 3;
    const float* paE[2]; const float* paC[2];
    int aw[2][4];
    #pragma unroll
    for (int g = 0; g < 2; ++g) {
        int r = r0 + g * 64;
        int m = m0 + r; if (m > M_TOT - 1) m = M_TOT - 1;
        int b = m / 1023;
        int t = m - b * 1023;
        paE[g] = events   + ((size_t)(b * L_ + t)) * H_;
        paC[g] = contexts + ((size_t)(b * (L_ - 1) + t)) * H_;
        #pragma unroll
        for (int j = 0; j < 4; ++j)
            aw[g][j] = r * 64 + (((2 * j + (q >> 1)) ^ (r & 7)) << 3)
                     + (q & 1) * 4;
    }

    // ---- B fragment bases: frag (j, ks) at bbJ + t*32768 + ks*16384 ----
    // (u16 units; per instr each 16-lane kg-group reads 256B contiguous)
    const u16* bb0 = wtp + (size_t)kg * 4096 + (nb * 128 + wn +  0 + lr) * 8;
    const u16* bb1 = wtp + (size_t)kg * 4096 + (nb * 128 + wn + 16 + lr) * 8;
    const u16* bb2 = wtp + (size_t)kg * 4096 + (nb * 128 + wn + 32 + lr) * 8;
    const u16* bb3 = wtp + (size_t)kg * 4096 + (nb * 128 + wn + 48 + lr) * 8;

    // ---- A fragment read offsets (u16, swizzled; chunk cw = ks*4+kg) ----
    int aoff[4][2];
    #pragma unroll
    for (int i = 0; i < 4; ++i) {
        int row = wm + i * 16 + lr;
        #pragma unroll
        for (int ks = 0; ks < 2; ++ks)
            aoff[i][ks] = row * 64 + (((ks * 4 + kg) ^ (row & 7)) << 3);
    }

    f32x4 acc[4][4];
    #pragma unroll
    for (int i = 0; i < 4; ++i)
        #pragma unroll
        for (int j = 0; j < 4; ++j)
            acc[i][j] = (f32x4){0.f, 0.f, 0.f, 0.f};

    // Named register sets (no arrays -> no scratch)
    f32x4 P0, P1, P2, P3, P4, P5, P6, P7;
    f32x4 Q0, Q1, Q2, Q3, Q4, Q5, Q6, Q7;
    short8 BX0, BX1, BX2, BX3, BX4, BX5, BX6, BX7;   // idx = j*2+ks
    short8 BY0, BY1, BY2, BY3, BY4, BY5, BY6, BY7;

#define BFRAG(p, KT)                                                           \
    {                                                                          \
        const u16* o_ = (const u16*)0 + (size_t)(KT) * 32768;                  \
        p##0 = *(const short8*)(bb0 + (size_t)(KT) * 32768);                   \
        p##1 = *(const short8*)(bb0 + (size_t)(KT) * 32768 + 16384);           \
        p##2 = *(const short8*)(bb1 + (size_t)(KT) * 32768);                   \
        p##3 = *(const short8*)(bb1 + (size_t)(KT) * 32768 + 16384);           \
        p##4 = *(const short8*)(bb2 + (size_t)(KT) * 32768);                   \
        p##5 = *(const short8*)(bb2 + (size_t)(KT) * 32768 + 16384);           \
        p##6 = *(const short8*)(bb3 + (size_t)(KT) * 32768);                   \
        p##7 = *(const short8*)(bb3 + (size_t)(KT) * 32768 + 16384);           \
        (void)o_;                                                              \
    }

#define LOADA(p, KT)                                                           \
    {                                                                          \
        int k0_ = (KT) * 64;                                                   \
        int rg_ = (KT) >> 4;                                                   \
        int kq_ = (k0_ & 1023) + q * 4;                                        \
        const float* s0_ = (rg_ == 0) ? paE[0]                                 \
                          : (rg_ == 1 ? (paE[0] + H_) : paC[0]);               \
        const float* s1_ = (rg_ == 0) ? paE[1]                                 \
                          : (rg_ == 1 ? (paE[1] + H_) : paC[1]);               \
        s0_ += kq_; s1_ += kq_;                                                \
        p##0 = *(const f32x4*)(s0_ +  0);                                      \
        p##1 = *(const f32x4*)(s0_ + 16);                                      \
        p##2 = *(const f32x4*)(s0_ + 32);                                      \
        p##3 = *(const f32x4*)(s0_ + 48);                                      \
        p##4 = *(const f32x4*)(s1_ +  0);                                      \
        p##5 = *(const f32x4*)(s1_ + 16);                                      \
        p##6 = *(const f32x4*)(s1_ + 32);                                      \
        p##7 = *(const f32x4*)(s1_ + 48);                                      \
    }
#define CVT1(p, RI, G, J, BUF)                                                 \
    {                                                                          \
        uint32_t lo_, hi_;                                                     \
        asm("v_cvt_pk_bf16_f32 %0, %1, %2" : "=v"(lo_) : "v"(p##RI[0]), "v"(p##RI[1])); \
        asm("v_cvt_pk_bf16_f32 %0, %1, %2" : "=v"(hi_) : "v"(p##RI[2]), "v"(p##RI[3])); \
        *(u32x2*)&Ab[BUF][aw[G][J]] = (u32x2){lo_, hi_};                       \
    }
#define CVTW(p, BUF)                                                           \
    CVT1(p, 0, 0, 0, BUF) CVT1(p, 1, 0, 1, BUF)                                \
    CVT1(p, 2, 0, 2, BUF) CVT1(p, 3, 0, 3, BUF)                                \
    CVT1(p, 4, 1, 0, BUF) CVT1(p, 5, 1, 1, BUF)                                \
    CVT1(p, 6, 1, 2, BUF) CVT1(p, 7, 1, 3, BUF)

#define COMPUTE(BUF, p)                                                        \
    {                                                                          \
        short8 a0_, a1_, a2_, a3_;                                             \
        /* ks = 0 */                                                           \
        a0_ = *(const short8*)&Ab[BUF][aoff[0][0]];                            \
        a1_ = *(const short8*)&Ab[BUF][aoff[1][0]];                            \
        a2_ = *(const short8*)&Ab[BUF][aoff[2][0]];                            \
        a3_ = *(const short8*)&Ab[BUF][aoff[3][0]];                            \
        __builtin_amdgcn_s_setprio(1);                                         \
        acc[0][0] = __builtin_amdgcn_mfma_f32_16x16x32_bf16(a0_, p##0, acc[0][0], 0, 0, 0); \
        acc[0][1] = __builtin_amdgcn_mfma_f32_16x16x32_bf16(a0_, p##2, acc[0][1], 0, 0, 0); \
        acc[0][2] = __builtin_amdgcn_mfma_f32_16x16x32_bf16(a0_, p##4, acc[0][2], 0, 0, 0); \
        acc[0][3] = __builtin_amdgcn_mfma_f32_16x16x32_bf16(a0_, p##6, acc[0][3], 0, 0, 0); \
        acc[1][0] = __builtin_amdgcn_mfma_f32_16x16x32_bf16(a1_, p##0, acc[1][0], 0, 0, 0); \
        acc[1][1] = __builtin_amdgcn_mfma_f32_16x16x32_bf16(a1_, p##2, acc[1][1], 0, 0, 0); \
        acc[1][2] = __builtin_amdgcn_mfma_f32_16x16x32_bf16(a1_, p##4, acc[1][2], 0, 0, 0); \
        acc[1][3] = __builtin_amdgcn_mfma_f32_16x16x32_bf16(a1_, p##6, acc[1][3], 0, 0, 0); \
        acc[2][0] = __builtin_amdgcn_mfma_f32_16x16x32_bf16(a2_, p##0, acc[2][0], 0, 0, 0); \
        acc[2][1] = __builtin_amdgcn_mfma_f32_16x16x32_bf16(a2_, p##2, acc[2][1], 0, 0, 0); \
        acc[2][2] = __builtin_amdgcn_mfma_f32_16x16x32_bf16(a2_, p##4, acc[2][2], 0, 0, 0); \
        acc[2][3] = __builtin_amdgcn_mfma_f32_16x16x32_bf16(a2_, p##6, acc[2][3], 0, 0, 0); \
        acc[3][0] = __builtin_amdgcn_mfma_f32_16x16x32_bf16(a3_, p##0, acc[3][0], 0, 0, 0); \
        acc[3][1] = __builtin_amdgcn_mfma_f32_16x16x32_bf16(a3_, p##2, acc[3][1], 0, 0, 0); \
        acc[3][2] = __builtin_amdgcn_mfma_f32_16x16x32_bf16(a3_, p##4, acc[3][2], 0, 0, 0); \
        acc[3][3] = __builtin_amdgcn_mfma_f32_16x16x32_bf16(a3_, p##6, acc[3][3], 0, 0, 0); \
        __builtin_amdgcn_s_setprio(0);                                         \
        /* ks = 1 */                                                           \
        a0_ = *(const short8*)&Ab[BUF][aoff[0][1]];                            \
        a1_ = *(const short8*)&Ab[BUF][aoff[1][1]];                            \
        a2_ = *(const short8*)&Ab[BUF][aoff[2][1]];                            \
        a3_ = *(const short8*)&Ab[BUF][aoff[3][1]];                            \
        __builtin_amdgcn_s_setprio(1);                                         \
        acc[0][0] = __builtin_amdgcn_mfma_f32_16x16x32_bf16(a0_, p##1, acc[0][0], 0, 0, 0); \
        acc[0][1] = __builtin_amdgcn_mfma_f32_16x16x32_bf16(a0_, p##3, acc[0][1], 0, 0, 0); \
        acc[0][2] = __builtin_amdgcn_mfma_f32_16x16x32_bf16(a0_, p##5, acc[0][2], 0, 0, 0); \
        acc[0][3] = __builtin_amdgcn_mfma_f32_16x16x32_bf16(a0_, p##7, acc[0][3], 0, 0, 0); \
        acc[1][0] = __builtin_amdgcn_mfma_f32_16x16x32_bf16(a1_, p##1, acc[1][0], 0, 0, 0); \
        acc[1][1] = __builtin_amdgcn_mfma_f32_16x16x32_bf16(a1_, p##3, acc[1][1], 0, 0, 0); \
        acc[1][2] = __builtin_amdgcn_mfma_f32_16x16x32_bf16(a1_, p##5, acc[1][2], 0, 0, 0); \
        acc[1][3] = __builtin_amdgcn_mfma_f32_16x16x32_bf16(a1_, p##7, acc[1][3], 0, 0, 0); \
        acc[2][0] = __builtin_amdgcn_mfma_f32_16x16x32_bf16(a2_, p##1, acc[2][0], 0, 0, 0); \
        acc[2][1] = __builtin_amdgcn_mfma_f32_16x16x32_bf16(a2_, p##3, acc[2][1], 0, 0, 0); \
        acc[2][2] = __builtin_amdgcn_mfma_f32_16x16x32_bf16(a2_, p##5, acc[2][2], 0, 0, 0); \
        acc[2][3] = __builtin_amdgcn_mfma_f32_16x16x32_bf16(a2_, p##7, acc[2][3], 0, 0, 0); \
        acc[3][0] = __builtin_amdgcn_mfma_f32_16x16x32_bf16(a3_, p##1, acc[3][0], 0, 0, 0); \
        acc[3][1] = __builtin_amdgcn_mfma_f32_16x16x32_bf16(a3_, p##3, acc[3][1], 0, 0, 0); \
        acc[3][2] = __builtin_amdgcn_mfma_f32_16x16x32_bf16(a3_, p##5, acc[3][2], 0, 0, 0); \
        acc[3][3] = __builtin_amdgcn_mfma_f32_16x16x32_bf16(a3_, p##7, acc[3][3], 0, 0, 0); \
        __builtin_amdgcn_s_setprio(0);                                         \
    }

#define WAITV(N)                                                               \
    asm volatile("s_waitcnt vmcnt(" #N ")" ::: "memory");                      \
    __builtin_amdgcn_sched_barrier(0);
#define LGKM0                                                                  \
    asm volatile("s_waitcnt lgkmcnt(0)" ::: "memory");                         \
    __builtin_amdgcn_sched_barrier(0);
#define BAR __builtin_amdgcn_s_barrier()

    // prologue: A(0)->regs->Ab[0]; BX=B(0) in flight; Q=A(1) in flight
    LOADA(P, 0);
    BFRAG(BX, 0);
    WAITV(8);            // drain P=A(0) regs; BX(0) stays in flight
    CVTW(P, 0);
    LOADA(Q, 1);         // outstanding: {BX(0) 8, Q(1) 8} = 16
    LGKM0;               // prologue ds_writes done before first barrier
    BAR;

    for (int t = 0; t < 46; t += 2) {
        // even phase t: consume BX=B(t), Ab[0]; Q holds A(t+1)
        BFRAG(BY, t + 1);
        LOADA(P, t + 2);
        WAITV(16); BAR;                // drains BX(t) + Q(t+1)
        COMPUTE(0, BX);
        CVTW(Q, 1);
        LGKM0; BAR;
        // odd phase t+1: consume BY=B(t+1), Ab[1]; P holds A(t+2)
        BFRAG(BX, t + 2);
        LOADA(Q, t + 3);
        WAITV(16); BAR;                // drains BY(t+1) + P(t+2)
        COMPUTE(1, BY);
        CVTW(P, 0);
        LGKM0; BAR;
    }
    // phase 46: consume BX(46); Q holds A(47); issue BY(47) only
    BFRAG(BY, 47);
    WAITV(8); BAR;                     // drains BX(46) + Q(47); BY(47) stays
    COMPUTE(0, BX);
    CVTW(Q, 1);
    LGKM0; BAR;
    // phase 47
    WAITV(0);
    COMPUTE(1, BY);

#undef BFRAG
#undef LOADA
#undef CVT1
#undef CVTW
#undef COMPUTE
#undef WAITV
#undef LGKM0
#undef BAR

    // epilogue: row = m0 + wm + i*16 + kg*4 + rr ; gcol = nb*128 + wn + j*16 + lr
    const float* bptr = bias + nb * 128;
    float* obase = out + (size_t)nb * OUT_SEG;
    #pragma unroll
    for (int i = 0; i < 4; ++i) {
        int mloc = wm + i * 16 + kg * 4;
        #pragma unroll
        for (int j = 0; j < 4; ++j) {
            int g = wn + j * 16 + lr;
            float bv = bptr[g];
            #pragma unroll
            for (int rr = 0; rr < 4; ++rr) {
                int mo = m0 + mloc + rr;
                if (mo < M_TOT) obase[(size_t)mo * G_ + g] = acc[i][j][rr] + bv;
            }
        }
    }
}

// ---------------- KL reduction: stage 1 (per-block partials, no atomics) -----
__global__ __launch_bounds__(256) void kl_kernel(const float* __restrict__ out,
                                                 float* __restrict__ partial)
{
    int wid  = threadIdx.x >> 6;
    int row  = blockIdx.x * 4 + wid;        // M_TOT = 4092*4 exactly
    int lane = threadIdx.x & 63;
    const float* zm  = out;
    const float* zlv = out + OUT_SEG;
    const float* qm  = out + (size_t)2 * OUT_SEG;
    const float* qlv = out + (size_t)3 * OUT_SEG;
    size_t base = (size_t)row * G_;
    float s = 0.f;
    #pragma unroll
    for (int hh = 0; hh < 2; ++hh) {
        int g = lane + hh * 64;
        float a = zm[base + g], b = zlv[base + g];
        float c = qm[base + g], d = qlv[base + g];
        float diff = a - c;
        s += d - b + (__expf(b) + diff * diff) * __expf(-d) - 1.0f;
    }
    #pragma unroll
    for (int off = 32; off > 0; off >>= 1)
        s += __shfl_down(s, off);
    __shared__ float pw[4];
    if (lane == 0) pw[wid] = s;
    __syncthreads();
    if (threadIdx.x == 0)
        partial[blockIdx.x] = pw[0] + pw[1] + pw[2] + pw[3];
}

// ---------------- KL reduction: stage 2 --------------------------------------
__global__ __launch_bounds__(256) void kl_final(const float* __restrict__ partial,
                                                float* __restrict__ out)
{
    float s = 0.f;
    for (int i = threadIdx.x; i < KL_BLOCKS; i += 256) s += partial[i];
    #pragma unroll
    for (int off = 32; off > 0; off >>= 1)
        s += __shfl_down(s, off);
    __shared__ float pw[4];
    int wid = threadIdx.x >> 6;
    int lane = threadIdx.x & 63;
    if (lane == 0) pw[wid] = s;
    __syncthreads();
    if (threadIdx.x == 0)
        out[KL_IDX] = 0.5f * (pw[0] + pw[1] + pw[2] + pw[3]) / (float)M_TOT;
}

// ---------------- launcher ----------------------------------------------------
extern "C" void kernel_launch(void* const* d_in, const int* in_sizes, int n_in,
                              void* d_out, int out_size, void* d_ws, size_t ws_size,
                              hipStream_t stream)
{
    const float* events   = (const float*)d_in[0];
    const float* contexts = (const float*)d_in[1];
    const float* Wzm = (const float*)d_in[2];
    const float* bzm = (const float*)d_in[3];
    const float* Wzv = (const float*)d_in[4];
    const float* bzv = (const float*)d_in[5];
    const float* Wqm = (const float*)d_in[6];
    const float* bqm = (const float*)d_in[7];
    const float* Wqv = (const float*)d_in[8];
    const float* bqv = (const float*)d_in[9];
    float* out = (float*)d_out;

    u16*   wtp     = (u16*)((char*)d_ws + WS_WTP_OFF);
    float* bias    = (float*)((char*)d_ws + WS_BIAS_OFF);
    float* partial = (float*)((char*)d_ws + WS_PART_OFF);

    prep_kernel<<<512, 256, 0, stream>>>(Wzm, bzm, Wzv, bzv, Wqm, bqm, Wqv, bqv,
                                         wtp, bias);
    gemm_kernel<<<512, 256, 0, stream>>>(events, contexts, wtp, bias, out);
    kl_kernel<<<KL_BLOCKS, 256, 0, stream>>>(out, partial);
    kl_final<<<1, 256, 0, stream>>>(partial, out);
}

// Round 19
// 95.787 us; speedup vs baseline: 1.1103x; 1.1103x over previous
//
#include <hip/hip_runtime.h>
#include <stdint.h>

typedef unsigned short u16;
typedef __attribute__((ext_vector_type(8))) short short8;
typedef __attribute__((ext_vector_type(4))) float f32x4;
typedef __attribute__((ext_vector_type(2))) uint32_t u32x2;
typedef __attribute__((ext_vector_type(2))) float f32x2;

#define B_      16
#define L_      1024
#define H_      1024
#define G_      128
#define M_TOT   16368            // B*(L-1)
#define K_TOT   3072
#define OUT_SEG 2095104          // M_TOT*G_
#define KL_IDX  (4*OUT_SEG)
#define KL_BLOCKS 4092           // M_TOT / 4 exactly

// ws layout
#define WS_WT_OFF    0           // bf16 W'T [512][3072] = 3,145,728 B
#define WS_BIAS_OFF  3145728     // float[512]
#define WS_PART_OFF  3147776     // float[4092] block partials

__device__ inline u16 f2bf(float f) {
    union { float f; uint32_t u; } x; x.f = f;
    uint32_t u = x.u;
    return (u16)((u + 0x7fffu + ((u >> 16) & 1u)) >> 16);
}

__device__ inline void gload16(const void* g, void* l) {
    __builtin_amdgcn_global_load_lds(
        (const __attribute__((address_space(1))) void*)g,
        (__attribute__((address_space(3))) void*)l, 16, 0, 0);
}

// ---------------- prep: build W'T (bf16, [512][3072]) + bias[512] ------------
// Transposed-tile version: 256 blocks = 64 n-groups (8 cols) x 4 k-quarters.
// Reads W in 32B segments (8 cols at once, 8x fewer cache lines than the
// old column-scalar version), transposes via padded LDS, writes wt in
// 512B-contiguous runs per n.
__global__ __launch_bounds__(256) void prep_kernel(
    const float* __restrict__ Wzm, const float* __restrict__ bzm,
    const float* __restrict__ Wzv, const float* __restrict__ bzv,
    const float* __restrict__ Wqm, const float* __restrict__ bqm,
    const float* __restrict__ Wqv, const float* __restrict__ bqv,
    u16* __restrict__ wt, float* __restrict__ bias)
{
    const int ng = blockIdx.x >> 2;        // 0..63 -> n0 = ng*8
    const int kq = blockIdx.x & 3;         // k in [kq*768, kq*768+768)
    const int n0 = ng * 8;                 // all 8 n in the same matrix
    const float* W; const float* bsrc; int g0; int kmax;
    if (n0 < 128)      { W = Wzm; bsrc = bzm; g0 = n0;       kmax = 2048; }
    else if (n0 < 256) { W = Wzv; bsrc = bzv; g0 = n0 - 128; kmax = 2048; }
    else if (n0 < 384) { W = Wqm; bsrc = bqm; g0 = n0 - 256; kmax = 3072; }
    else               { W = Wqv; bsrc = bqv; g0 = n0 - 384; kmax = 3072; }
    const int tid = threadIdx.x;
    if (kq == 0 && tid < 8) bias[n0 + tid] = bsrc[g0 + tid];

    __shared__ float lt[8][260];           // padded: conflict-free writes
    const int go = tid & 7;                // read role: column within group
    const int kk = tid >> 3;               // read role: k mod 32
    const int nn = tid >> 5;               // write role: n within group
    const int kc = (tid & 31) * 8;         // write role: k-octet base

    for (int i = 0; i < 3; ++i) {
        int kbase = kq * 768 + i * 256;
        __syncthreads();
        #pragma unroll
        for (int kk2 = 0; kk2 < 8; ++kk2) {
            int k = kbase + kk2 * 32 + kk;
            float v = (k < kmax) ? W[(size_t)k * G_ + g0 + go] : 0.0f;
            lt[go][kk2 * 32 + kk] = v;
        }
        __syncthreads();
        union { short8 s; u16 u[8]; } o;
        #pragma unroll
        for (int j = 0; j < 8; ++j) o.u[j] = f2bf(lt[nn][kc + j]);
        *(short8*)&wt[(size_t)(n0 + nn) * K_TOT + kbase + kc] = o.s;
    }
}

// ---------------- GEMM: out[m, 0:512] = ce @ W' + bias ----------------------
// R17 champion, byte-identical. BM=128, BN=128, BK=64, 4 waves (2x2 of
// 64x64), grid 512 -> 2 independent blocks/CU. LDS = 2*(16KB A + 16KB B).
//   A: global f32x4 (64B coalesced) -> named P/Q reg sets (2-deep)
//      -> cvt_pk bf16 -> swizzled ds_write_b64.
//   B: global_load_lds source-preswizzled.
// Counted vmcnt: 12 VMEM/phase (8 A + 4 B); WAITV(12) drains B(t)+Aregs(t+1).
// Swizzles: A/B rows = 128B = 8 chunks of 16B, chunk ^= (row&7).
__global__ __launch_bounds__(256, 2) void gemm_kernel(
    const float* __restrict__ events, const float* __restrict__ contexts,
    const u16* __restrict__ wt, const float* __restrict__ bias,
    float* __restrict__ out)
{
    __shared__ u16 Ab[2][128 * 64];   // bf16 A tiles, swizzled (16 KB each)
    __shared__ u16 Bs[2][128 * 64];   // bf16 B tiles, swizzled (16 KB each)

    const int tid = threadIdx.x;
    const int bid = blockIdx.x;
    // 4 nb-blocks of an A panel share bid&7 -> same XCD.
    const int xx  = bid & 7;
    const int jj  = bid >> 3;            // 0..63
    const int nb  = jj & 3;
    const int mp  = (jj >> 2) * 8 + xx;  // 0..127
    const int m0  = mp * 128;

    const int lane = tid & 63;
    const int w    = tid >> 6;           // 0..3
    const int wm   = (w >> 1) * 64;
    const int wn   = (w & 1) * 64;
    const int lr   = lane & 15;
    const int kg   = lane >> 4;          // 0..3

    // ---- A staging: rows r0=tid>>2 and r0+64; q=tid&3; 8 f32x4 loads.
    const int r0 = tid >> 2;
    const int q  = tid & 3;
    const float* paE[2]; const float* paC[2];
    int aw[2][4];
    #pragma unroll
    for (int g = 0; g < 2; ++g) {
        int r = r0 + g * 64;
        int m = m0 + r; if (m > M_TOT - 1) m = M_TOT - 1;
        int b = m / 1023;
        int t = m - b * 1023;
        paE[g] = events   + ((size_t)(b * L_ + t)) * H_;
        paC[g] = contexts + ((size_t)(b * (L_ - 1) + t)) * H_;
        #pragma unroll
        for (int j = 0; j < 4; ++j)
            aw[g][j] = r * 64 + (((2 * j + (q >> 1)) ^ (r & 7)) << 3)
                     + (q & 1) * 4;
    }

    // ---- B staging: 4 gload_lds chunks/thread, source-preswizzled ----
    const u16* bS[4];
    #pragma unroll
    for (int it = 0; it < 4; ++it) {
        int c  = it * 256 + tid;
        int v  = c >> 3;
        int cs = (c & 7) ^ (v & 7);
        bS[it] = wt + (size_t)(nb * 128 + v) * K_TOT + cs * 8;
    }

    // ---- fragment read offsets (u16, swizzled; chunk cw = ks*4+kg) ----
    int aoff[4][2], boff[4][2];
    #pragma unroll
    for (int i = 0; i < 4; ++i) {
        int row = wm + i * 16 + lr;
        int nn  = wn + i * 16 + lr;
        #pragma unroll
        for (int ks = 0; ks < 2; ++ks) {
            aoff[i][ks] = row * 64 + (((ks * 4 + kg) ^ (row & 7)) << 3);
            boff[i][ks] = nn  * 64 + (((ks * 4 + kg) ^ (nn  & 7)) << 3);
        }
    }

    f32x4 acc[4][4];
    #pragma unroll
    for (int i = 0; i < 4; ++i)
        #pragma unroll
        for (int j = 0; j < 4; ++j)
            acc[i][j] = (f32x4){0.f, 0.f, 0.f, 0.f};

    auto stageB = [&](int buf, int kt) {
        int k0 = kt * 64;
        #pragma unroll
        for (int it = 0; it < 4; ++it)
            gload16(bS[it] + k0, &Bs[buf][(it * 256 + tid) * 8]);
    };
    auto compute = [&](int buf) {
        #pragma unroll
        for (int ks = 0; ks < 2; ++ks) {
            short8 a[4], bf[4];
            #pragma unroll
            for (int i = 0; i < 4; ++i)
                a[i] = *(const short8*)&Ab[buf][aoff[i][ks]];
            #pragma unroll
            for (int j = 0; j < 4; ++j)
                bf[j] = *(const short8*)&Bs[buf][boff[j][ks]];
            __builtin_amdgcn_s_setprio(1);
            #pragma unroll
            for (int i = 0; i < 4; ++i)
                #pragma unroll
                for (int j = 0; j < 4; ++j)
                    acc[i][j] = __builtin_amdgcn_mfma_f32_16x16x32_bf16(
                        a[i], bf[j], acc[i][j], 0, 0, 0);
            __builtin_amdgcn_s_setprio(0);
        }
    };

    // Named A-staging register sets (2-phase-deep; no arrays -> no scratch)
    f32x4 P0, P1, P2, P3, P4, P5, P6, P7;
    f32x4 Q0, Q1, Q2, Q3, Q4, Q5, Q6, Q7;

#define LOADA(p, KT)                                                           \
    {                                                                          \
        int k0_ = (KT) * 64;                                                   \
        int rg_ = (KT) >> 4;                                                   \
        int kq_ = (k0_ & 1023) + q * 4;                                        \
        const float* s0_ = (rg_ == 0) ? paE[0]                                 \
                          : (rg_ == 1 ? (paE[0] + H_) : paC[0]);               \
        const float* s1_ = (rg_ == 0) ? paE[1]                                 \
                          : (rg_ == 1 ? (paE[1] + H_) : paC[1]);               \
        s0_ += kq_; s1_ += kq_;                                                \
        p##0 = *(const f32x4*)(s0_ +  0);                                      \
        p##1 = *(const f32x4*)(s0_ + 16);                                      \
        p##2 = *(const f32x4*)(s0_ + 32);                                      \
        p##3 = *(const f32x4*)(s0_ + 48);                                      \
        p##4 = *(const f32x4*)(s1_ +  0);                                      \
        p##5 = *(const f32x4*)(s1_ + 16);                                      \
        p##6 = *(const f32x4*)(s1_ + 32);                                      \
        p##7 = *(const f32x4*)(s1_ + 48);                                      \
    }
#define CVT1(p, RI, G, J, BUF)                                                 \
    {                                                                          \
        uint32_t lo_, hi_;                                                     \
        asm("v_cvt_pk_bf16_f32 %0, %1, %2" : "=v"(lo_) : "v"(p##RI[0]), "v"(p##RI[1])); \
        asm("v_cvt_pk_bf16_f32 %0, %1, %2" : "=v"(hi_) : "v"(p##RI[2]), "v"(p##RI[3])); \
        *(u32x2*)&Ab[BUF][aw[G][J]] = (u32x2){lo_, hi_};                       \
    }
#define CVTW(p, BUF)                                                           \
    CVT1(p, 0, 0, 0, BUF) CVT1(p, 1, 0, 1, BUF)                                \
    CVT1(p, 2, 0, 2, BUF) CVT1(p, 3, 0, 3, BUF)                                \
    CVT1(p, 4, 1, 0, BUF) CVT1(p, 5, 1, 1, BUF)                                \
    CVT1(p, 6, 1, 2, BUF) CVT1(p, 7, 1, 3, BUF)

#define WAITV(N)                                                               \
    asm volatile("s_waitcnt vmcnt(" #N ")" ::: "memory");                      \
    __builtin_amdgcn_sched_barrier(0);
#define LGKM0                                                                  \
    asm volatile("s_waitcnt lgkmcnt(0)" ::: "memory");                         \
    __builtin_amdgcn_sched_barrier(0);
#define BAR __builtin_amdgcn_s_barrier()

    // prologue: A(0)->regs->Ab[0]; B(0) in flight; A(1)->Q (in flight)
    LOADA(P, 0);
    stageB(0, 0);
    WAITV(4);            // drain P = A(0) regs, leave B(0)
    CVTW(P, 0);
    LOADA(Q, 1);         // outstanding: B(0) 4 + Q 8 = 12
    LGKM0;               // prologue ds_writes done before first barrier

    for (int t = 0; t < 46; t += 2) {
        // phase t (buf0): consume Q=A(t+1) after WAITV
        LOADA(P, t + 2);
        stageB(1, t + 1);
        WAITV(12); BAR;                // drains B(t) + Q regs
        compute(0);
        CVTW(Q, 1);
        LGKM0; BAR;
        // phase t+1 (buf1)
        LOADA(Q, t + 3);
        stageB(0, t + 2);
        WAITV(12); BAR;                // drains B(t+1) + P regs
        compute(1);
        CVTW(P, 0);
        LGKM0; BAR;
    }
    // phase 46 (buf0): Q holds A(47); no more A loads
    stageB(1, 47);
    WAITV(4); BAR;                     // drains B(46) + Q regs, leaves B(47)
    compute(0);
    CVTW(Q, 1);
    LGKM0; BAR;
    // phase 47 (buf1)
    WAITV(0); BAR;
    compute(1);

#undef LOADA
#undef CVT1
#undef CVTW
#undef WAITV
#undef LGKM0
#undef BAR

    // epilogue: row = m0 + wm + i*16 + kg*4 + rr ; gcol = nb*128 + wn + j*16 + lr
    const float* bptr = bias + nb * 128;
    float* obase = out + (size_t)nb * OUT_SEG;
    #pragma unroll
    for (int i = 0; i < 4; ++i) {
        int mloc = wm + i * 16 + kg * 4;
        #pragma unroll
        for (int j = 0; j < 4; ++j) {
            int g = wn + j * 16 + lr;
            float bv = bptr[g];
            #pragma unroll
            for (int rr = 0; rr < 4; ++rr) {
                int mo = m0 + mloc + rr;
                if (mo < M_TOT) obase[(size_t)mo * G_ + g] = acc[i][j][rr] + bv;
            }
        }
    }
}

// ---------------- KL reduction: stage 1 (f32x2 loads, no atomics) ------------
__global__ __launch_bounds__(256) void kl_kernel(const float* __restrict__ out,
                                                 float* __restrict__ partial)
{
    int wid  = threadIdx.x >> 6;
    int row  = blockIdx.x * 4 + wid;        // M_TOT = 4092*4 exactly
    int lane = threadIdx.x & 63;
    const float* zm  = out;
    const float* zlv = out + OUT_SEG;
    const float* qm  = out + (size_t)2 * OUT_SEG;
    const float* qlv = out + (size_t)3 * OUT_SEG;
    size_t base = (size_t)row * G_ + lane * 2;
    f32x2 a = *(const f32x2*)&zm[base];
    f32x2 b = *(const f32x2*)&zlv[base];
    f32x2 c = *(const f32x2*)&qm[base];
    f32x2 d = *(const f32x2*)&qlv[base];
    float s = 0.f;
    #pragma unroll
    for (int e = 0; e < 2; ++e) {
        float diff = a[e] - c[e];
        s += d[e] - b[e] + (__expf(b[e]) + diff * diff) * __expf(-d[e]) - 1.0f;
    }
    #pragma unroll
    for (int off = 32; off > 0; off >>= 1)
        s += __shfl_down(s, off);
    __shared__ float pw[4];
    if (lane == 0) pw[wid] = s;
    __syncthreads();
    if (threadIdx.x == 0)
        partial[blockIdx.x] = pw[0] + pw[1] + pw[2] + pw[3];
}

// ---------------- KL reduction: stage 2 --------------------------------------
__global__ __launch_bounds__(256) void kl_final(const float* __restrict__ partial,
                                                float* __restrict__ out)
{
    float s = 0.f;
    for (int i = threadIdx.x; i < KL_BLOCKS; i += 256) s += partial[i];
    #pragma unroll
    for (int off = 32; off > 0; off >>= 1)
        s += __shfl_down(s, off);
    __shared__ float pw[4];
    int wid = threadIdx.x >> 6;
    int lane = threadIdx.x & 63;
    if (lane == 0) pw[wid] = s;
    __syncthreads();
    if (threadIdx.x == 0)
        out[KL_IDX] = 0.5f * (pw[0] + pw[1] + pw[2] + pw[3]) / (float)M_TOT;
}

// ---------------- launcher ----------------------------------------------------
extern "C" void kernel_launch(void* const* d_in, const int* in_sizes, int n_in,
                              void* d_out, int out_size, void* d_ws, size_t ws_size,
                              hipStream_t stream)
{
    const float* events   = (const float*)d_in[0];
    const float* contexts = (const float*)d_in[1];
    const float* Wzm = (const float*)d_in[2];
    const float* bzm = (const float*)d_in[3];
    const float* Wzv = (const float*)d_in[4];
    const float* bzv = (const float*)d_in[5];
    const float* Wqm = (const float*)d_in[6];
    const float* bqm = (const float*)d_in[7];
    const float* Wqv = (const float*)d_in[8];
    const float* bqv = (const float*)d_in[9];
    float* out = (float*)d_out;

    u16*   wt      = (u16*)((char*)d_ws + WS_WT_OFF);
    float* bias    = (float*)((char*)d_ws + WS_BIAS_OFF);
    float* partial = (float*)((char*)d_ws + WS_PART_OFF);

    prep_kernel<<<256, 256, 0, stream>>>(Wzm, bzm, Wzv, bzv, Wqm, bqm, Wqv, bqv,
                                         wt, bias);
    gemm_kernel<<<512, 256, 0, stream>>>(events, contexts, wt, bias, out);
    kl_kernel<<<KL_BLOCKS, 256, 0, stream>>>(out, partial);
    kl_final<<<1, 256, 0, stream>>>(partial, out);
}